// Round 1
// baseline (7698.778 us; speedup 1.0000x reference)
//
#include <hip/hip_runtime.h>
#include <cstdint>
#include <cmath>

typedef unsigned short u16;
typedef __bf16 v8bf __attribute__((ext_vector_type(8)));
typedef float v4f __attribute__((ext_vector_type(4)));

__device__ __forceinline__ u16 f2bf(float f) {
    unsigned int u = __float_as_uint(f);
    u += 0x7fffu + ((u >> 16) & 1u);   // round-to-nearest-even
    return (u16)(u >> 16);
}
__device__ __forceinline__ float sigmoidf_(float x) { return 1.0f / (1.0f + __expf(-x)); }
__device__ __forceinline__ float tanhf_(float x) {
    float e = __expf(2.0f * x);
    return 1.0f - 2.0f / (e + 1.0f);
}

// ---------------------------------------------------------------------------
// Fused LSTM-layer GEMM: gates = [A1|A2] @ W^T + bias, then cell update.
// A1: [1024][S1] bf16 (first K1 cols of K), A2: [1024][S2] bf16 (rest).
// W:  [4096][Ktot] bf16, rows reordered j' = unit*4 + gate (i,f,g,o).
// Epilogue: c' = f*c + i*g ; h = o*tanh(c') ; Cst fp32 in-place, Hout bf16.
// Tile: BM=64 x BN=128, BK=64, 256 threads (4 waves, each 32x64).
// ---------------------------------------------------------------------------
__global__ __launch_bounds__(256)
void lstm_gemm(const u16* __restrict__ A1, int K1, int S1,
               const u16* __restrict__ A2, int S2,
               const u16* __restrict__ W, int Ktot,
               const float* __restrict__ bias,
               float* __restrict__ Cst,
               u16* __restrict__ Hout)
{
    __shared__ alignas(16) float smem[64 * 132];   // 33792 B; aliased for staging
    u16* At = (u16*)smem;        // [64][64]
    u16* Bt = At + 64 * 64;      // [128][64]

    const int tid  = threadIdx.x;
    const int wave = tid >> 6;
    const int lane = tid & 63;
    const int l16  = lane & 15;
    const int lq   = lane >> 4;
    const int wr   = wave >> 1;      // 0..1 -> row offset wr*32
    const int wc   = wave & 1;       // 0..1 -> col offset wc*64
    const int m0   = blockIdx.y * 64;
    const int n0   = blockIdx.x * 128;

    v4f acc[2][4];
#pragma unroll
    for (int i = 0; i < 2; ++i)
#pragma unroll
        for (int j = 0; j < 4; ++j) acc[i][j] = (v4f){0.f, 0.f, 0.f, 0.f};

    for (int k0 = 0; k0 < Ktot; k0 += 64) {
        // ---- stage A tile (64x64 bf16 = 512 x 16B chunks) via global_load_lds
        const u16* Asrc; int kof, st;
        if (k0 < K1) { Asrc = A1; kof = k0;      st = S1; }
        else         { Asrc = A2; kof = k0 - K1; st = S2; }
#pragma unroll
        for (int r = 0; r < 2; ++r) {
            int c = tid + r * 256;
            int row = c >> 3, kc = c & 7;
            const u16* g = Asrc + (size_t)(m0 + row) * st + kof + kc * 8;
            __builtin_amdgcn_global_load_lds(
                (const __attribute__((address_space(1))) unsigned int*)g,
                (__attribute__((address_space(3))) unsigned int*)(At + c * 8),
                16, 0, 0);
        }
        // ---- stage B tile (128x64 bf16 = 1024 x 16B chunks)
#pragma unroll
        for (int r = 0; r < 4; ++r) {
            int c = tid + r * 256;
            int row = c >> 3, kc = c & 7;
            const u16* g = W + (size_t)(n0 + row) * Ktot + k0 + kc * 8;
            __builtin_amdgcn_global_load_lds(
                (const __attribute__((address_space(1))) unsigned int*)g,
                (__attribute__((address_space(3))) unsigned int*)(Bt + c * 8),
                16, 0, 0);
        }
        asm volatile("s_waitcnt vmcnt(0)" ::: "memory");
        __syncthreads();

#pragma unroll
        for (int kk = 0; kk < 64; kk += 32) {
            v8bf a[2], b[4];
#pragma unroll
            for (int mi = 0; mi < 2; ++mi)
                a[mi] = *(const v8bf*)(At + (wr * 32 + mi * 16 + l16) * 64 + kk + lq * 8);
#pragma unroll
            for (int ni = 0; ni < 4; ++ni)
                b[ni] = *(const v8bf*)(Bt + (wc * 64 + ni * 16 + l16) * 64 + kk + lq * 8);
#pragma unroll
            for (int mi = 0; mi < 2; ++mi)
#pragma unroll
                for (int ni = 0; ni < 4; ++ni)
                    acc[mi][ni] = __builtin_amdgcn_mfma_f32_16x16x32_bf16(
                        a[mi], b[ni], acc[mi][ni], 0, 0, 0);
        }
        __syncthreads();
    }

    // ---- epilogue: gates -> LDS (+bias), then fused cell update
    float* gates = smem;   // [64][132]
#pragma unroll
    for (int mi = 0; mi < 2; ++mi)
#pragma unroll
        for (int ni = 0; ni < 4; ++ni) {
            int col = wc * 64 + ni * 16 + l16;
            float bs = bias[n0 + col];
#pragma unroll
            for (int r = 0; r < 4; ++r) {
                int row = wr * 32 + mi * 16 + lq * 4 + r;  // C-layout: row=(lane>>4)*4+reg
                gates[row * 132 + col] = acc[mi][ni][r] + bs;
            }
        }
    __syncthreads();

#pragma unroll
    for (int it = tid; it < 64 * 32; it += 256) {
        int row = it >> 5, u = it & 31;
        const float* gp = gates + row * 132 + u * 4;
        float gi = gp[0], gf = gp[1], gg = gp[2], go = gp[3];
        int b = m0 + row;
        int U = (n0 >> 2) + u;               // global hidden-unit index
        float c  = Cst[b * 1024 + U];
        float i_ = sigmoidf_(gi);
        float f_ = sigmoidf_(gf);
        float g_ = tanhf_(gg);
        float o_ = sigmoidf_(go);
        float c2 = f_ * c + i_ * g_;
        float h  = o_ * tanhf_(c2);
        Cst[b * 1024 + U]  = c2;
        Hout[b * 1024 + U] = f2bf(h);
    }
}

// ---------------------------------------------------------------------------
// Decoder head: delta = h1 @ fc_w^T + fc_b ; LN(delta)*alpha+beta + dec_prev
// grid 16 x 256 threads; each wave: 16 batch rows x 80 cols (66 valid), MFMA.
// ---------------------------------------------------------------------------
__global__ __launch_bounds__(256)
void fc_ln_kernel(const u16* __restrict__ H1, const u16* __restrict__ Wf,
                  const float* __restrict__ fcb, const float* __restrict__ alpha,
                  const float* __restrict__ beta,
                  const float* __restrict__ decprev, float* __restrict__ outp,
                  u16* __restrict__ decnext)
{
    const int tid  = threadIdx.x;
    const int wave = tid >> 6, lane = tid & 63;
    const int l16  = lane & 15, lq = lane >> 4;
    const int b0   = blockIdx.x * 64 + wave * 16;

    v4f acc[5];
#pragma unroll
    for (int i = 0; i < 5; ++i) acc[i] = (v4f){0.f, 0.f, 0.f, 0.f};

    for (int k = 0; k < 1024; k += 32) {
        v8bf a = *(const v8bf*)(H1 + (size_t)(b0 + l16) * 1024 + k + lq * 8);
#pragma unroll
        for (int ni = 0; ni < 5; ++ni) {
            v8bf bb = *(const v8bf*)(Wf + (size_t)(ni * 16 + l16) * 1024 + k + lq * 8);
            acc[ni] = __builtin_amdgcn_mfma_f32_16x16x32_bf16(a, bb, acc[ni], 0, 0, 0);
        }
    }

    float av[5], bv[5], fb[5]; int valid[5];
#pragma unroll
    for (int ni = 0; ni < 5; ++ni) {
        int col = ni * 16 + l16;
        valid[ni] = col < 66;
        fb[ni] = valid[ni] ? fcb[col]   : 0.f;
        av[ni] = valid[ni] ? alpha[col] : 0.f;
        bv[ni] = valid[ni] ? beta[col]  : 0.f;
    }
#pragma unroll
    for (int r = 0; r < 4; ++r) {
        int b = b0 + lq * 4 + r;
        float d[5];
        float s = 0.f;
#pragma unroll
        for (int ni = 0; ni < 5; ++ni) {
            d[ni] = valid[ni] ? (acc[ni][r] + fb[ni]) : 0.f;
            s += d[ni];
        }
#pragma unroll
        for (int m = 1; m < 16; m <<= 1) s += __shfl_xor(s, m, 64);
        float mean = s * (1.f / 66.f);
        float vs = 0.f;
#pragma unroll
        for (int ni = 0; ni < 5; ++ni) {
            float t = valid[ni] ? (d[ni] - mean) : 0.f;
            vs += t * t;
        }
#pragma unroll
        for (int m = 1; m < 16; m <<= 1) vs += __shfl_xor(vs, m, 64);
        float inv = rsqrtf(vs * (1.f / 66.f) + 1e-5f);
#pragma unroll
        for (int ni = 0; ni < 5; ++ni) {
            if (valid[ni]) {
                int col = ni * 16 + l16;
                float y = (d[ni] - mean) * inv * av[ni] + bv[ni]
                        + decprev[(size_t)b * 3300 + col];
                outp[(size_t)b * 3300 + col] = y;
                decnext[b * 128 + col] = f2bf(y);
            }
        }
    }
}

// ---------------------------------------------------------------------------
// init kernels: weight reorder/convert (gate-interleaved rows), x->bf16, zeros
// ---------------------------------------------------------------------------
__global__ void k_init_w0(const float* __restrict__ Wih, const float* __restrict__ Whh,
                          u16* __restrict__ Wc)
{
    int idx = blockIdx.x * 256 + threadIdx.x;
    if (idx >= 4096 * 1152) return;
    int jp = idx / 1152, k = idx - jp * 1152;
    int u = jp >> 2, g = jp & 3;           // j' = u*4+g  <-  j = g*1024+u
    float v = 0.f;
    if (k < 66)        v = Wih[(g * 1024 + u) * 66 + k];
    else if (k >= 128) v = Whh[(size_t)(g * 1024 + u) * 1024 + (k - 128)];
    Wc[idx] = f2bf(v);
}
__global__ void k_init_w1(const float* __restrict__ Wih, const float* __restrict__ Whh,
                          u16* __restrict__ Wc)
{
    int idx = blockIdx.x * 256 + threadIdx.x;   // 4096*2048
    int jp = idx >> 11, k = idx & 2047;
    int u = jp >> 2, g = jp & 3;
    float v = (k < 1024) ? Wih[(size_t)(g * 1024 + u) * 1024 + k]
                         : Whh[(size_t)(g * 1024 + u) * 1024 + (k - 1024)];
    Wc[idx] = f2bf(v);
}
__global__ void k_init_fcw(const float* __restrict__ fcw, u16* __restrict__ Wb)
{
    int idx = blockIdx.x * 256 + threadIdx.x;   // 80*1024
    int r = idx >> 10, k = idx & 1023;
    float v = (r < 66) ? fcw[(size_t)r * 1024 + k] : 0.f;
    Wb[idx] = f2bf(v);
}
__global__ void k_init_bias(const float* __restrict__ b0, const float* __restrict__ b1,
                            float* __restrict__ B0p, float* __restrict__ B1p)
{
    int idx = blockIdx.x * 256 + threadIdx.x;   // 8192
    if (idx < 4096) B0p[idx] = b0[(idx & 3) * 1024 + (idx >> 2)];
    else { int j = idx - 4096; B1p[j] = b1[(j & 3) * 1024 + (j >> 2)]; }
}
__global__ void k_init_x(const float* __restrict__ x, u16* __restrict__ Xbuf,
                         u16* __restrict__ DEC0)
{
    int idx = blockIdx.x * 256 + threadIdx.x;   // 50*1024*128
    int t = idx >> 17;
    int b = (idx >> 7) & 1023;
    int c = idx & 127;
    float v = (c < 66) ? x[(size_t)b * 3300 + t * 66 + c] : 0.f;
    u16 h = f2bf(v);
    if (t < 49) Xbuf[idx] = h;
    else        DEC0[b * 128 + c] = h;
}
__global__ void k_init_state(u16* __restrict__ H0z, u16* __restrict__ H1z,
                             float* __restrict__ C0, float* __restrict__ C1,
                             u16* __restrict__ DEC1)
{
    int idx = blockIdx.x * 256 + threadIdx.x;   // 1024*1024
    H0z[idx] = 0; H1z[idx] = 0;
    C0[idx] = 0.f; C1[idx] = 0.f;
    if (idx < 1024 * 128) DEC1[idx] = 0;
}

// ---------------------------------------------------------------------------
extern "C" void kernel_launch(void* const* d_in, const int* in_sizes, int n_in,
                              void* d_out, int out_size, void* d_ws, size_t ws_size,
                              hipStream_t stream)
{
    const float* x     = (const float*)d_in[0];
    const float* Wih0  = (const float*)d_in[1];
    const float* Whh0  = (const float*)d_in[2];
    const float* b0    = (const float*)d_in[3];
    const float* Wih1  = (const float*)d_in[4];
    const float* Whh1  = (const float*)d_in[5];
    const float* b1    = (const float*)d_in[6];
    const float* fcw   = (const float*)d_in[7];
    const float* fcb   = (const float*)d_in[8];
    const float* alpha = (const float*)d_in[9];
    const float* beta  = (const float*)d_in[10];
    float* out = (float*)d_out;

    char* p = (char*)d_ws;
    auto take = [&](size_t bytes) { char* r = p; p += (bytes + 255) & ~(size_t)255; return r; };
    u16*   Wc0  = (u16*)take((size_t)4096 * 1152 * 2);
    u16*   Wc1  = (u16*)take((size_t)4096 * 2048 * 2);
    u16*   fcwb = (u16*)take((size_t)80 * 1024 * 2);
    float* B0p  = (float*)take(4096 * 4);
    float* B1p  = (float*)take(4096 * 4);
    u16*   Xbuf = (u16*)take((size_t)49 * 1024 * 128 * 2);
    u16*   DEC  = (u16*)take((size_t)2 * 1024 * 128 * 2);
    u16*   H0   = (u16*)take((size_t)2 * 1024 * 1024 * 2);
    u16*   H1   = (u16*)take((size_t)2 * 1024 * 1024 * 2);
    float* C0   = (float*)take((size_t)1024 * 1024 * 4);
    float* C1   = (float*)take((size_t)1024 * 1024 * 4);

    k_init_w0<<<18432, 256, 0, stream>>>(Wih0, Whh0, Wc0);
    k_init_w1<<<32768, 256, 0, stream>>>(Wih1, Whh1, Wc1);
    k_init_fcw<<<320, 256, 0, stream>>>(fcw, fcwb);
    k_init_bias<<<32, 256, 0, stream>>>(b0, b1, B0p, B1p);
    k_init_x<<<25600, 256, 0, stream>>>(x, Xbuf, DEC);
    k_init_state<<<4096, 256, 0, stream>>>(H0, H1, C0, C1, DEC + 1024 * 128);

    const size_t HSZ = 1024 * 1024;
    dim3 ggrid(32, 16);   // N-tiles x M-tiles
    for (int s = 0; s < 99; ++s) {
        const u16* A1;
        if (s < 49) A1 = Xbuf + (size_t)s * (1024 * 128);
        else        A1 = DEC + (size_t)((s - 49) & 1) * (1024 * 128);
        u16* h0r = H0 + (size_t)(s & 1) * HSZ;
        u16* h0w = H0 + (size_t)((s + 1) & 1) * HSZ;
        u16* h1r = H1 + (size_t)(s & 1) * HSZ;
        u16* h1w = H1 + (size_t)((s + 1) & 1) * HSZ;

        lstm_gemm<<<ggrid, 256, 0, stream>>>(A1, 128, 128, h0r, 1024,
                                             Wc0, 1152, B0p, C0, h0w);
        lstm_gemm<<<ggrid, 256, 0, stream>>>(h0w, 1024, 1024, h1r, 1024,
                                             Wc1, 2048, B1p, C1, h1w);
        if (s >= 49) {
            int d = s - 49;
            const float* decprev = (d == 0) ? (x + 49 * 66) : (out + (size_t)(d - 1) * 66);
            fc_ln_kernel<<<dim3(16), 256, 0, stream>>>(h1w, fcwb, fcb, alpha, beta,
                                                       decprev, out + (size_t)d * 66,
                                                       DEC + (size_t)((d + 1) & 1) * (1024 * 128));
        }
    }
}

// Round 2
// 6750.793 us; speedup vs baseline: 1.1404x; 1.1404x over previous
//
#include <hip/hip_runtime.h>
#include <cstdint>
#include <cmath>

typedef unsigned short u16;
typedef __bf16 v8bf __attribute__((ext_vector_type(8)));
typedef float v4f __attribute__((ext_vector_type(4)));

__device__ __forceinline__ u16 f2bf(float f) {
    unsigned int u = __float_as_uint(f);
    u += 0x7fffu + ((u >> 16) & 1u);   // round-to-nearest-even
    return (u16)(u >> 16);
}
__device__ __forceinline__ float sigmoidf_(float x) { return 1.0f / (1.0f + __expf(-x)); }
__device__ __forceinline__ float tanhf_(float x) {
    float e = __expf(2.0f * x);
    return 1.0f - 2.0f / (e + 1.0f);
}

// ---------------------------------------------------------------------------
// Fused LSTM-layer GEMM: gates = [A1|A2] @ W^T + bias, then cell update.
// LDS tiles use a 16B-chunk XOR swizzle: global chunk (row, kc^(row&7)) is
// stored at linear chunk position row*8+kc (global_load_lds forces LDS pos =
// lane-linear). Fragment reads then hit 8 distinct 4-bank groups per quad
// (2-way aliasing = free) instead of a 16-way single-bank conflict.
// Tile: BM=64 x BN=128, BK=64, 256 threads (4 waves, each 32x64).
// ---------------------------------------------------------------------------
__global__ __launch_bounds__(256)
void lstm_gemm(const u16* __restrict__ A1, int K1, int S1,
               const u16* __restrict__ A2, int S2,
               const u16* __restrict__ W, int Ktot,
               const float* __restrict__ bias,
               float* __restrict__ Cst,
               u16* __restrict__ Hout)
{
    __shared__ alignas(16) float smem[64 * 132];   // 33792 B; aliased for staging
    u16* At = (u16*)smem;        // [64][8 chunks] of 16B
    u16* Bt = At + 64 * 64;      // [128][8 chunks]

    const int tid  = threadIdx.x;
    const int wave = tid >> 6;
    const int lane = tid & 63;
    const int l16  = lane & 15;
    const int lq   = lane >> 4;
    const int wr   = wave >> 1;      // 0..1 -> row offset wr*32
    const int wc   = wave & 1;       // 0..1 -> col offset wc*64
    const int m0   = blockIdx.y * 64;
    const int n0   = blockIdx.x * 128;

    v4f acc[2][4];
#pragma unroll
    for (int i = 0; i < 2; ++i)
#pragma unroll
        for (int j = 0; j < 4; ++j) acc[i][j] = (v4f){0.f, 0.f, 0.f, 0.f};

    for (int k0 = 0; k0 < Ktot; k0 += 64) {
        // ---- stage A tile (64x64 bf16 = 512 x 16B chunks), XOR-swizzled source
        const u16* Asrc; int kof, st;
        if (k0 < K1) { Asrc = A1; kof = k0;      st = S1; }
        else         { Asrc = A2; kof = k0 - K1; st = S2; }
#pragma unroll
        for (int r = 0; r < 2; ++r) {
            int c = tid + r * 256;
            int row = c >> 3;
            int kc  = (c & 7) ^ (row & 7);
            const u16* g = Asrc + (size_t)(m0 + row) * st + kof + kc * 8;
            __builtin_amdgcn_global_load_lds(
                (const __attribute__((address_space(1))) unsigned int*)g,
                (__attribute__((address_space(3))) unsigned int*)(At + c * 8),
                16, 0, 0);
        }
        // ---- stage B tile (128x64 bf16 = 1024 x 16B chunks), XOR-swizzled
#pragma unroll
        for (int r = 0; r < 4; ++r) {
            int c = tid + r * 256;
            int row = c >> 3;
            int kc  = (c & 7) ^ (row & 7);
            const u16* g = W + (size_t)(n0 + row) * Ktot + k0 + kc * 8;
            __builtin_amdgcn_global_load_lds(
                (const __attribute__((address_space(1))) unsigned int*)g,
                (__attribute__((address_space(3))) unsigned int*)(Bt + c * 8),
                16, 0, 0);
        }
        asm volatile("s_waitcnt vmcnt(0)" ::: "memory");
        __syncthreads();

#pragma unroll
        for (int kk = 0; kk < 64; kk += 32) {
            const int kcb = kk >> 3;             // base 16B-chunk index (0 or 4)
            v8bf a[2], b[4];
#pragma unroll
            for (int mi = 0; mi < 2; ++mi) {
                int row = wr * 32 + mi * 16 + l16;
                int p = row * 8 + ((kcb + lq) ^ (row & 7));
                a[mi] = *(const v8bf*)(At + p * 8);
            }
#pragma unroll
            for (int ni = 0; ni < 4; ++ni) {
                int row = wc * 64 + ni * 16 + l16;
                int p = row * 8 + ((kcb + lq) ^ (row & 7));
                b[ni] = *(const v8bf*)(Bt + p * 8);
            }
#pragma unroll
            for (int mi = 0; mi < 2; ++mi)
#pragma unroll
                for (int ni = 0; ni < 4; ++ni)
                    acc[mi][ni] = __builtin_amdgcn_mfma_f32_16x16x32_bf16(
                        a[mi], b[ni], acc[mi][ni], 0, 0, 0);
        }
        __syncthreads();
    }

    // ---- epilogue: gates -> LDS (+bias), then fused cell update
    float* gates = smem;   // [64][132]
#pragma unroll
    for (int mi = 0; mi < 2; ++mi)
#pragma unroll
        for (int ni = 0; ni < 4; ++ni) {
            int col = wc * 64 + ni * 16 + l16;
            float bs = bias[n0 + col];
#pragma unroll
            for (int r = 0; r < 4; ++r) {
                int row = wr * 32 + mi * 16 + lq * 4 + r;  // C-layout: row=(lane>>4)*4+reg
                gates[row * 132 + col] = acc[mi][ni][r] + bs;
            }
        }
    __syncthreads();

#pragma unroll
    for (int it = tid; it < 64 * 32; it += 256) {
        int row = it >> 5, u = it & 31;
        const float* gp = gates + row * 132 + u * 4;
        float gi = gp[0], gf = gp[1], gg = gp[2], go = gp[3];
        int b = m0 + row;
        int U = (n0 >> 2) + u;               // global hidden-unit index
        float c  = Cst[b * 1024 + U];
        float i_ = sigmoidf_(gi);
        float f_ = sigmoidf_(gf);
        float g_ = tanhf_(gg);
        float o_ = sigmoidf_(go);
        float c2 = f_ * c + i_ * g_;
        float h  = o_ * tanhf_(c2);
        Cst[b * 1024 + U]  = c2;
        Hout[b * 1024 + U] = f2bf(h);
    }
}

// ---------------------------------------------------------------------------
// Decoder head: delta = h1 @ fc_w^T + fc_b ; LN(delta)*alpha+beta + dec_prev
// grid 16 x 256 threads; each wave: 16 batch rows x 80 cols (66 valid), MFMA.
// ---------------------------------------------------------------------------
__global__ __launch_bounds__(256)
void fc_ln_kernel(const u16* __restrict__ H1, const u16* __restrict__ Wf,
                  const float* __restrict__ fcb, const float* __restrict__ alpha,
                  const float* __restrict__ beta,
                  const float* __restrict__ decprev, float* __restrict__ outp,
                  u16* __restrict__ decnext)
{
    const int tid  = threadIdx.x;
    const int wave = tid >> 6, lane = tid & 63;
    const int l16  = lane & 15, lq = lane >> 4;
    const int b0   = blockIdx.x * 64 + wave * 16;

    v4f acc[5];
#pragma unroll
    for (int i = 0; i < 5; ++i) acc[i] = (v4f){0.f, 0.f, 0.f, 0.f};

    for (int k = 0; k < 1024; k += 32) {
        v8bf a = *(const v8bf*)(H1 + (size_t)(b0 + l16) * 1024 + k + lq * 8);
#pragma unroll
        for (int ni = 0; ni < 5; ++ni) {
            v8bf bb = *(const v8bf*)(Wf + (size_t)(ni * 16 + l16) * 1024 + k + lq * 8);
            acc[ni] = __builtin_amdgcn_mfma_f32_16x16x32_bf16(a, bb, acc[ni], 0, 0, 0);
        }
    }

    float av[5], bv[5], fb[5]; int valid[5];
#pragma unroll
    for (int ni = 0; ni < 5; ++ni) {
        int col = ni * 16 + l16;
        valid[ni] = col < 66;
        fb[ni] = valid[ni] ? fcb[col]   : 0.f;
        av[ni] = valid[ni] ? alpha[col] : 0.f;
        bv[ni] = valid[ni] ? beta[col]  : 0.f;
    }
#pragma unroll
    for (int r = 0; r < 4; ++r) {
        int b = b0 + lq * 4 + r;
        float d[5];
        float s = 0.f;
#pragma unroll
        for (int ni = 0; ni < 5; ++ni) {
            d[ni] = valid[ni] ? (acc[ni][r] + fb[ni]) : 0.f;
            s += d[ni];
        }
#pragma unroll
        for (int m = 1; m < 16; m <<= 1) s += __shfl_xor(s, m, 64);
        float mean = s * (1.f / 66.f);
        float vs = 0.f;
#pragma unroll
        for (int ni = 0; ni < 5; ++ni) {
            float t = valid[ni] ? (d[ni] - mean) : 0.f;
            vs += t * t;
        }
#pragma unroll
        for (int m = 1; m < 16; m <<= 1) vs += __shfl_xor(vs, m, 64);
        float inv = rsqrtf(vs * (1.f / 66.f) + 1e-5f);
#pragma unroll
        for (int ni = 0; ni < 5; ++ni) {
            if (valid[ni]) {
                int col = ni * 16 + l16;
                float y = (d[ni] - mean) * inv * av[ni] + bv[ni]
                        + decprev[(size_t)b * 3300 + col];
                outp[(size_t)b * 3300 + col] = y;
                decnext[b * 128 + col] = f2bf(y);
            }
        }
    }
}

// ---------------------------------------------------------------------------
// init kernels: weight reorder/convert (gate-interleaved rows), x->bf16, zeros
// ---------------------------------------------------------------------------
__global__ void k_init_w0(const float* __restrict__ Wih, const float* __restrict__ Whh,
                          u16* __restrict__ Wc)
{
    int idx = blockIdx.x * 256 + threadIdx.x;
    if (idx >= 4096 * 1152) return;
    int jp = idx / 1152, k = idx - jp * 1152;
    int u = jp >> 2, g = jp & 3;           // j' = u*4+g  <-  j = g*1024+u
    float v = 0.f;
    if (k < 66)        v = Wih[(g * 1024 + u) * 66 + k];
    else if (k >= 128) v = Whh[(size_t)(g * 1024 + u) * 1024 + (k - 128)];
    Wc[idx] = f2bf(v);
}
__global__ void k_init_w1(const float* __restrict__ Wih, const float* __restrict__ Whh,
                          u16* __restrict__ Wc)
{
    int idx = blockIdx.x * 256 + threadIdx.x;   // 4096*2048
    int jp = idx >> 11, k = idx & 2047;
    int u = jp >> 2, g = jp & 3;
    float v = (k < 1024) ? Wih[(size_t)(g * 1024 + u) * 1024 + k]
                         : Whh[(size_t)(g * 1024 + u) * 1024 + (k - 1024)];
    Wc[idx] = f2bf(v);
}
__global__ void k_init_fcw(const float* __restrict__ fcw, u16* __restrict__ Wb)
{
    int idx = blockIdx.x * 256 + threadIdx.x;   // 80*1024
    int r = idx >> 10, k = idx & 1023;
    float v = (r < 66) ? fcw[(size_t)r * 1024 + k] : 0.f;
    Wb[idx] = f2bf(v);
}
__global__ void k_init_bias(const float* __restrict__ b0, const float* __restrict__ b1,
                            float* __restrict__ B0p, float* __restrict__ B1p)
{
    int idx = blockIdx.x * 256 + threadIdx.x;   // 8192
    if (idx < 4096) B0p[idx] = b0[(idx & 3) * 1024 + (idx >> 2)];
    else { int j = idx - 4096; B1p[j] = b1[(j & 3) * 1024 + (j >> 2)]; }
}
__global__ void k_init_x(const float* __restrict__ x, u16* __restrict__ Xbuf,
                         u16* __restrict__ DEC0)
{
    int idx = blockIdx.x * 256 + threadIdx.x;   // 50*1024*128
    int t = idx >> 17;
    int b = (idx >> 7) & 1023;
    int c = idx & 127;
    float v = (c < 66) ? x[(size_t)b * 3300 + t * 66 + c] : 0.f;
    u16 h = f2bf(v);
    if (t < 49) Xbuf[idx] = h;
    else        DEC0[b * 128 + c] = h;
}
__global__ void k_init_state(u16* __restrict__ H0z, u16* __restrict__ H1z,
                             float* __restrict__ C0, float* __restrict__ C1,
                             u16* __restrict__ DEC1)
{
    int idx = blockIdx.x * 256 + threadIdx.x;   // 1024*1024
    H0z[idx] = 0; H1z[idx] = 0;
    C0[idx] = 0.f; C1[idx] = 0.f;
    if (idx < 1024 * 128) DEC1[idx] = 0;
}

// ---------------------------------------------------------------------------
extern "C" void kernel_launch(void* const* d_in, const int* in_sizes, int n_in,
                              void* d_out, int out_size, void* d_ws, size_t ws_size,
                              hipStream_t stream)
{
    const float* x     = (const float*)d_in[0];
    const float* Wih0  = (const float*)d_in[1];
    const float* Whh0  = (const float*)d_in[2];
    const float* b0    = (const float*)d_in[3];
    const float* Wih1  = (const float*)d_in[4];
    const float* Whh1  = (const float*)d_in[5];
    const float* b1    = (const float*)d_in[6];
    const float* fcw   = (const float*)d_in[7];
    const float* fcb   = (const float*)d_in[8];
    const float* alpha = (const float*)d_in[9];
    const float* beta  = (const float*)d_in[10];
    float* out = (float*)d_out;

    char* p = (char*)d_ws;
    auto take = [&](size_t bytes) { char* r = p; p += (bytes + 255) & ~(size_t)255; return r; };
    u16*   Wc0  = (u16*)take((size_t)4096 * 1152 * 2);
    u16*   Wc1  = (u16*)take((size_t)4096 * 2048 * 2);
    u16*   fcwb = (u16*)take((size_t)80 * 1024 * 2);
    float* B0p  = (float*)take(4096 * 4);
    float* B1p  = (float*)take(4096 * 4);
    u16*   Xbuf = (u16*)take((size_t)49 * 1024 * 128 * 2);
    u16*   DEC  = (u16*)take((size_t)2 * 1024 * 128 * 2);
    u16*   H0   = (u16*)take((size_t)2 * 1024 * 1024 * 2);
    u16*   H1   = (u16*)take((size_t)2 * 1024 * 1024 * 2);
    float* C0   = (float*)take((size_t)1024 * 1024 * 4);
    float* C1   = (float*)take((size_t)1024 * 1024 * 4);

    k_init_w0<<<18432, 256, 0, stream>>>(Wih0, Whh0, Wc0);
    k_init_w1<<<32768, 256, 0, stream>>>(Wih1, Whh1, Wc1);
    k_init_fcw<<<320, 256, 0, stream>>>(fcw, fcwb);
    k_init_bias<<<32, 256, 0, stream>>>(b0, b1, B0p, B1p);
    k_init_x<<<25600, 256, 0, stream>>>(x, Xbuf, DEC);
    k_init_state<<<4096, 256, 0, stream>>>(H0, H1, C0, C1, DEC + 1024 * 128);

    const size_t HSZ = 1024 * 1024;
    dim3 ggrid(32, 16);   // N-tiles x M-tiles
    for (int s = 0; s < 99; ++s) {
        const u16* A1;
        if (s < 49) A1 = Xbuf + (size_t)s * (1024 * 128);
        else        A1 = DEC + (size_t)((s - 49) & 1) * (1024 * 128);
        u16* h0r = H0 + (size_t)(s & 1) * HSZ;
        u16* h0w = H0 + (size_t)((s + 1) & 1) * HSZ;
        u16* h1r = H1 + (size_t)(s & 1) * HSZ;
        u16* h1w = H1 + (size_t)((s + 1) & 1) * HSZ;

        lstm_gemm<<<ggrid, 256, 0, stream>>>(A1, 128, 128, h0r, 1024,
                                             Wc0, 1152, B0p, C0, h0w);
        lstm_gemm<<<ggrid, 256, 0, stream>>>(h0w, 1024, 1024, h1r, 1024,
                                             Wc1, 2048, B1p, C1, h1w);
        if (s >= 49) {
            int d = s - 49;
            const float* decprev = (d == 0) ? (x + 49 * 66) : (out + (size_t)(d - 1) * 66);
            fc_ln_kernel<<<dim3(16), 256, 0, stream>>>(h1w, fcwb, fcb, alpha, beta,
                                                       decprev, out + (size_t)d * 66,
                                                       DEC + (size_t)((d + 1) & 1) * (1024 * 128));
        }
    }
}

// Round 3
// 6606.648 us; speedup vs baseline: 1.1653x; 1.0218x over previous
//
#include <hip/hip_runtime.h>
#include <cstdint>
#include <cmath>

typedef unsigned short u16;
typedef __bf16 v8bf __attribute__((ext_vector_type(8)));
typedef float v4f __attribute__((ext_vector_type(4)));

__device__ __forceinline__ u16 f2bf(float f) {
    unsigned int u = __float_as_uint(f);
    u += 0x7fffu + ((u >> 16) & 1u);   // round-to-nearest-even
    return (u16)(u >> 16);
}
__device__ __forceinline__ float sigmoidf_(float x) { return 1.0f / (1.0f + __expf(-x)); }
__device__ __forceinline__ float tanhf_(float x) {
    float e = __expf(2.0f * x);
    return 1.0f - 2.0f / (e + 1.0f);
}

// ---------------------------------------------------------------------------
// Fused LSTM-layer GEMM: gates = [A1|A2] @ W^T + bias, then cell update.
//   Tile: BM=128 x BN=128, BK=64, 256 threads = 4 waves (2x2), wave tile 64x64
//   (acc[4][4] of 16x16x32 bf16 MFMAs -> FLOP/LDS-byte = 32,
//    FLOP/global-byte = 64 -> both near the CU balance points).
//   Double-buffered LDS staging, software-pipelined: stage tile k+1 after the
//   barrier, compute tile k while those loads are in flight (the barrier's
//   implicit vmcnt(0) is free because nothing else is outstanding there).
//   16B-chunk XOR swizzle keeps fragment ds_read_b128 at 2-way (free) aliasing.
//   grid.x = n_tile so b%8 == n_tile%8 -> same W slice pinned to one XCD's L2
//   across all 99 steps (W0 slice 1.1 MB + W1 slice 2 MB < 4 MB L2/XCD).
// ---------------------------------------------------------------------------
__global__ __launch_bounds__(256)
void lstm_gemm(const u16* __restrict__ A1, int K1, int S1,
               const u16* __restrict__ A2, int S2,
               const u16* __restrict__ W, int Ktot,
               const float* __restrict__ bias,
               float* __restrict__ Cst,
               u16* __restrict__ Hout)
{
    // 64 KB: two 32 KB stage buffers; reused as 64x132 f32 gates in epilogue
    __shared__ alignas(16) u16 smem[32768];

    const int tid  = threadIdx.x;
    const int wave = tid >> 6;
    const int lane = tid & 63;
    const int l16  = lane & 15;
    const int lq   = lane >> 4;
    const int wrb  = (wave >> 1) * 64;    // wave row base within block tile
    const int wcb  = (wave & 1) * 64;     // wave col base
    const int m0   = blockIdx.y * 128;
    const int n0   = blockIdx.x * 128;

    v4f acc[4][4];
#pragma unroll
    for (int i = 0; i < 4; ++i)
#pragma unroll
        for (int j = 0; j < 4; ++j) acc[i][j] = (v4f){0.f, 0.f, 0.f, 0.f};

    // staging constants: thread handles chunks c = tid + r*256 (r=0..3 A, 0..3 B)
    const int srow = tid >> 3;            // + r*32
    const int skc  = tid & 7;             // ^ (row&7) applied per r

    auto stage_tile = [&](int k0, int buf) {
        u16* At = smem + buf * 16384;     // [128][8 chunks of 16B]
        u16* Bt = At + 8192;
        const u16* Asrc; int kof, st;
        if (k0 < K1) { Asrc = A1; kof = k0;      st = S1; }
        else         { Asrc = A2; kof = k0 - K1; st = S2; }
#pragma unroll
        for (int r = 0; r < 4; ++r) {
            int c = tid + r * 256;
            int row = srow + r * 32;
            int kc  = skc ^ (row & 7);
            const u16* g = Asrc + (size_t)(m0 + row) * st + kof + kc * 8;
            __builtin_amdgcn_global_load_lds(
                (const __attribute__((address_space(1))) unsigned int*)g,
                (__attribute__((address_space(3))) unsigned int*)(At + c * 8),
                16, 0, 0);
        }
#pragma unroll
        for (int r = 0; r < 4; ++r) {
            int c = tid + r * 256;
            int row = srow + r * 32;
            int kc  = skc ^ (row & 7);
            const u16* g = W + (size_t)(n0 + row) * Ktot + k0 + kc * 8;
            __builtin_amdgcn_global_load_lds(
                (const __attribute__((address_space(1))) unsigned int*)g,
                (__attribute__((address_space(3))) unsigned int*)(Bt + c * 8),
                16, 0, 0);
        }
    };

    const int nt = Ktot >> 6;
    stage_tile(0, 0);
    for (int it = 0; it < nt; ++it) {
        __syncthreads();                       // tile `it` landed (all waves)
        if (it + 1 < nt) stage_tile((it + 1) << 6, (it + 1) & 1);
        const u16* At = smem + (it & 1) * 16384;
        const u16* Bt = At + 8192;
#pragma unroll
        for (int kk = 0; kk < 64; kk += 32) {
            const int kcb = kk >> 3;           // base 16B-chunk (0 or 4)
            v8bf a[4], b[4];
#pragma unroll
            for (int mi = 0; mi < 4; ++mi) {
                int row = wrb + mi * 16 + l16;
                int p = row * 8 + ((kcb + lq) ^ (row & 7));
                a[mi] = *(const v8bf*)(At + p * 8);
            }
#pragma unroll
            for (int ni = 0; ni < 4; ++ni) {
                int row = wcb + ni * 16 + l16;
                int p = row * 8 + ((kcb + lq) ^ (row & 7));
                b[ni] = *(const v8bf*)(Bt + p * 8);
            }
#pragma unroll
            for (int mi = 0; mi < 4; ++mi)
#pragma unroll
                for (int ni = 0; ni < 4; ++ni)
                    acc[mi][ni] = __builtin_amdgcn_mfma_f32_16x16x32_bf16(
                        a[mi], b[ni], acc[mi][ni], 0, 0, 0);
        }
    }
    __syncthreads();

    // ---- epilogue in two row-halves (gates buffer 64x132 f32 = 33.8 KB)
    float* gates = (float*)smem;
#pragma unroll
    for (int p = 0; p < 2; ++p) {
        if ((wave >> 1) == p) {
#pragma unroll
            for (int mi = 0; mi < 4; ++mi)
#pragma unroll
                for (int ni = 0; ni < 4; ++ni) {
                    int col = wcb + ni * 16 + l16;
                    float bs = bias[n0 + col];
#pragma unroll
                    for (int r = 0; r < 4; ++r) {
                        int row = mi * 16 + lq * 4 + r;   // local within half
                        gates[row * 132 + col] = acc[mi][ni][r] + bs;
                    }
                }
        }
        __syncthreads();
#pragma unroll
        for (int j = 0; j < 8; ++j) {
            int it2 = tid + j * 256;
            int row = it2 >> 5, u = it2 & 31;
            const float* gp = gates + row * 132 + u * 4;
            float gi = gp[0], gf = gp[1], gg = gp[2], go = gp[3];
            int b = m0 + p * 64 + row;
            int U = (n0 >> 2) + u;
            float c  = Cst[b * 1024 + U];
            float i_ = sigmoidf_(gi);
            float f_ = sigmoidf_(gf);
            float g_ = tanhf_(gg);
            float o_ = sigmoidf_(go);
            float c2 = f_ * c + i_ * g_;
            float h  = o_ * tanhf_(c2);
            Cst[b * 1024 + U]  = c2;
            Hout[b * 1024 + U] = f2bf(h);
        }
        __syncthreads();
    }
}

// ---------------------------------------------------------------------------
// Decoder head: delta = h1 @ fc_w^T + fc_b ; LN(delta)*alpha+beta + dec_prev
// ---------------------------------------------------------------------------
__global__ __launch_bounds__(256)
void fc_ln_kernel(const u16* __restrict__ H1, const u16* __restrict__ Wf,
                  const float* __restrict__ fcb, const float* __restrict__ alpha,
                  const float* __restrict__ beta,
                  const float* __restrict__ decprev, float* __restrict__ outp,
                  u16* __restrict__ decnext)
{
    const int tid  = threadIdx.x;
    const int wave = tid >> 6, lane = tid & 63;
    const int l16  = lane & 15, lq = lane >> 4;
    const int b0   = blockIdx.x * 64 + wave * 16;

    v4f acc[5];
#pragma unroll
    for (int i = 0; i < 5; ++i) acc[i] = (v4f){0.f, 0.f, 0.f, 0.f};

    for (int k = 0; k < 1024; k += 32) {
        v8bf a = *(const v8bf*)(H1 + (size_t)(b0 + l16) * 1024 + k + lq * 8);
#pragma unroll
        for (int ni = 0; ni < 5; ++ni) {
            v8bf bb = *(const v8bf*)(Wf + (size_t)(ni * 16 + l16) * 1024 + k + lq * 8);
            acc[ni] = __builtin_amdgcn_mfma_f32_16x16x32_bf16(a, bb, acc[ni], 0, 0, 0);
        }
    }

    float av[5], bv[5], fb[5]; int valid[5];
#pragma unroll
    for (int ni = 0; ni < 5; ++ni) {
        int col = ni * 16 + l16;
        valid[ni] = col < 66;
        fb[ni] = valid[ni] ? fcb[col]   : 0.f;
        av[ni] = valid[ni] ? alpha[col] : 0.f;
        bv[ni] = valid[ni] ? beta[col]  : 0.f;
    }
#pragma unroll
    for (int r = 0; r < 4; ++r) {
        int b = b0 + lq * 4 + r;
        float d[5];
        float s = 0.f;
#pragma unroll
        for (int ni = 0; ni < 5; ++ni) {
            d[ni] = valid[ni] ? (acc[ni][r] + fb[ni]) : 0.f;
            s += d[ni];
        }
#pragma unroll
        for (int m = 1; m < 16; m <<= 1) s += __shfl_xor(s, m, 64);
        float mean = s * (1.f / 66.f);
        float vs = 0.f;
#pragma unroll
        for (int ni = 0; ni < 5; ++ni) {
            float t = valid[ni] ? (d[ni] - mean) : 0.f;
            vs += t * t;
        }
#pragma unroll
        for (int m = 1; m < 16; m <<= 1) vs += __shfl_xor(vs, m, 64);
        float inv = rsqrtf(vs * (1.f / 66.f) + 1e-5f);
#pragma unroll
        for (int ni = 0; ni < 5; ++ni) {
            if (valid[ni]) {
                int col = ni * 16 + l16;
                float y = (d[ni] - mean) * inv * av[ni] + bv[ni]
                        + decprev[(size_t)b * 3300 + col];
                outp[(size_t)b * 3300 + col] = y;
                decnext[b * 128 + col] = f2bf(y);
            }
        }
    }
}

// ---------------------------------------------------------------------------
// init kernels: weight reorder/convert (gate-interleaved rows), x->bf16, zeros
// ---------------------------------------------------------------------------
__global__ void k_init_w0(const float* __restrict__ Wih, const float* __restrict__ Whh,
                          u16* __restrict__ Wc)
{
    int idx = blockIdx.x * 256 + threadIdx.x;
    if (idx >= 4096 * 1152) return;
    int jp = idx / 1152, k = idx - jp * 1152;
    int u = jp >> 2, g = jp & 3;           // j' = u*4+g  <-  j = g*1024+u
    float v = 0.f;
    if (k < 66)        v = Wih[(g * 1024 + u) * 66 + k];
    else if (k >= 128) v = Whh[(size_t)(g * 1024 + u) * 1024 + (k - 128)];
    Wc[idx] = f2bf(v);
}
__global__ void k_init_w1(const float* __restrict__ Wih, const float* __restrict__ Whh,
                          u16* __restrict__ Wc)
{
    int idx = blockIdx.x * 256 + threadIdx.x;   // 4096*2048
    int jp = idx >> 11, k = idx & 2047;
    int u = jp >> 2, g = jp & 3;
    float v = (k < 1024) ? Wih[(size_t)(g * 1024 + u) * 1024 + k]
                         : Whh[(size_t)(g * 1024 + u) * 1024 + (k - 1024)];
    Wc[idx] = f2bf(v);
}
__global__ void k_init_fcw(const float* __restrict__ fcw, u16* __restrict__ Wb)
{
    int idx = blockIdx.x * 256 + threadIdx.x;   // 80*1024
    int r = idx >> 10, k = idx & 1023;
    float v = (r < 66) ? fcw[(size_t)r * 1024 + k] : 0.f;
    Wb[idx] = f2bf(v);
}
__global__ void k_init_bias(const float* __restrict__ b0, const float* __restrict__ b1,
                            float* __restrict__ B0p, float* __restrict__ B1p)
{
    int idx = blockIdx.x * 256 + threadIdx.x;   // 8192
    if (idx < 4096) B0p[idx] = b0[(idx & 3) * 1024 + (idx >> 2)];
    else { int j = idx - 4096; B1p[j] = b1[(j & 3) * 1024 + (j >> 2)]; }
}
__global__ void k_init_x(const float* __restrict__ x, u16* __restrict__ Xbuf,
                         u16* __restrict__ DEC0)
{
    int idx = blockIdx.x * 256 + threadIdx.x;   // 50*1024*128
    int t = idx >> 17;
    int b = (idx >> 7) & 1023;
    int c = idx & 127;
    float v = (c < 66) ? x[(size_t)b * 3300 + t * 66 + c] : 0.f;
    u16 h = f2bf(v);
    if (t < 49) Xbuf[idx] = h;
    else        DEC0[b * 128 + c] = h;
}
__global__ void k_init_state(u16* __restrict__ H0z, u16* __restrict__ H1z,
                             float* __restrict__ C0, float* __restrict__ C1,
                             u16* __restrict__ DEC1)
{
    int idx = blockIdx.x * 256 + threadIdx.x;   // 1024*1024
    H0z[idx] = 0; H1z[idx] = 0;
    C0[idx] = 0.f; C1[idx] = 0.f;
    if (idx < 1024 * 128) DEC1[idx] = 0;
}

// ---------------------------------------------------------------------------
extern "C" void kernel_launch(void* const* d_in, const int* in_sizes, int n_in,
                              void* d_out, int out_size, void* d_ws, size_t ws_size,
                              hipStream_t stream)
{
    const float* x     = (const float*)d_in[0];
    const float* Wih0  = (const float*)d_in[1];
    const float* Whh0  = (const float*)d_in[2];
    const float* b0    = (const float*)d_in[3];
    const float* Wih1  = (const float*)d_in[4];
    const float* Whh1  = (const float*)d_in[5];
    const float* b1    = (const float*)d_in[6];
    const float* fcw   = (const float*)d_in[7];
    const float* fcb   = (const float*)d_in[8];
    const float* alpha = (const float*)d_in[9];
    const float* beta  = (const float*)d_in[10];
    float* out = (float*)d_out;

    char* p = (char*)d_ws;
    auto take = [&](size_t bytes) { char* r = p; p += (bytes + 255) & ~(size_t)255; return r; };
    u16*   Wc0  = (u16*)take((size_t)4096 * 1152 * 2);
    u16*   Wc1  = (u16*)take((size_t)4096 * 2048 * 2);
    u16*   fcwb = (u16*)take((size_t)80 * 1024 * 2);
    float* B0p  = (float*)take(4096 * 4);
    float* B1p  = (float*)take(4096 * 4);
    u16*   Xbuf = (u16*)take((size_t)49 * 1024 * 128 * 2);
    u16*   DEC  = (u16*)take((size_t)2 * 1024 * 128 * 2);
    u16*   H0   = (u16*)take((size_t)2 * 1024 * 1024 * 2);
    u16*   H1   = (u16*)take((size_t)2 * 1024 * 1024 * 2);
    float* C0   = (float*)take((size_t)1024 * 1024 * 4);
    float* C1   = (float*)take((size_t)1024 * 1024 * 4);

    k_init_w0<<<18432, 256, 0, stream>>>(Wih0, Whh0, Wc0);
    k_init_w1<<<32768, 256, 0, stream>>>(Wih1, Whh1, Wc1);
    k_init_fcw<<<320, 256, 0, stream>>>(fcw, fcwb);
    k_init_bias<<<32, 256, 0, stream>>>(b0, b1, B0p, B1p);
    k_init_x<<<25600, 256, 0, stream>>>(x, Xbuf, DEC);
    k_init_state<<<4096, 256, 0, stream>>>(H0, H1, C0, C1, DEC + 1024 * 128);

    const size_t HSZ = 1024 * 1024;
    dim3 ggrid(32, 8);   // x = n_tile (XCD-pinned W slice), y = m_tile
    for (int s = 0; s < 99; ++s) {
        const u16* A1;
        if (s < 49) A1 = Xbuf + (size_t)s * (1024 * 128);
        else        A1 = DEC + (size_t)((s - 49) & 1) * (1024 * 128);
        u16* h0r = H0 + (size_t)(s & 1) * HSZ;
        u16* h0w = H0 + (size_t)((s + 1) & 1) * HSZ;
        u16* h1r = H1 + (size_t)(s & 1) * HSZ;
        u16* h1w = H1 + (size_t)((s + 1) & 1) * HSZ;

        lstm_gemm<<<ggrid, 256, 0, stream>>>(A1, 128, 128, h0r, 1024,
                                             Wc0, 1152, B0p, C0, h0w);
        lstm_gemm<<<ggrid, 256, 0, stream>>>(h0w, 1024, 1024, h1r, 1024,
                                             Wc1, 2048, B1p, C1, h1w);
        if (s >= 49) {
            int d = s - 49;
            const float* decprev = (d == 0) ? (x + 49 * 66) : (out + (size_t)(d - 1) * 66);
            fc_ln_kernel<<<dim3(16), 256, 0, stream>>>(h1w, fcwb, fcb, alpha, beta,
                                                       decprev, out + (size_t)d * 66,
                                                       DEC + (size_t)((d + 1) & 1) * (1024 * 128));
        }
    }
}